// Round 4
// baseline (1144.285 us; speedup 1.0000x reference)
//
#include <hip/hip_runtime.h>
#include <math.h>

constexpr int Bn = 8, Nn = 256, Dn = 768, Hn = 12, Kn = 128;
constexpr int Tn = Nn * Bn;      // 2048 tokens
constexpr float SCALE = 0.125f;  // HD^-0.5, HD=64
constexpr float NEGB = -1e9f;

typedef __attribute__((ext_vector_type(8))) short bf16x8;
typedef __attribute__((ext_vector_type(4))) float f32x4;

#define MFMA16(a, b, c) __builtin_amdgcn_mfma_f32_16x16x32_bf16((a), (b), (c), 0, 0, 0)

__device__ __forceinline__ void gload_lds16(const void* g, void* l) {
  __builtin_amdgcn_global_load_lds(
      (const __attribute__((address_space(1))) void*)g,
      (__attribute__((address_space(3))) void*)l, 16, 0, 0);
}

__device__ __forceinline__ ushort f2bf(float x) {  // round-to-nearest-even
  union { float f; unsigned u; } v; v.f = x;
  unsigned r = (v.u + 0x7fff + ((v.u >> 16) & 1)) >> 16;
  return (ushort)r;
}
__device__ __forceinline__ ushort f2bf_t(float x) {  // truncate (1 inst)
  union { float f; unsigned u; } v; v.f = x;
  return (ushort)(v.u >> 16);
}
__device__ __forceinline__ float bf2f(ushort u) {
  union { unsigned u; float f; } v; v.u = ((unsigned)u) << 16;
  return v.f;
}
// tanh-approx gelu (|err| <~3e-3)
__device__ __forceinline__ float gelu_fast(float x) {
  float u = x * (0.7978845608f + 0.0356774081f * x * x);
  float e = __expf(2.0f * u);
  float t = 1.0f - 2.0f / (e + 1.0f);
  return 0.5f * x * (1.0f + t);
}
__device__ __forceinline__ float wave_sum(float v) {
#pragma unroll
  for (int off = 32; off; off >>= 1) v += __shfl_xor(v, off);
  return v;
}

// ---------------- weight transpose+convert: W[K,N] f32 -> WT[N,K] bf16 -------
__global__ __launch_bounds__(256) void wtrans(const float* __restrict__ W,
                                              ushort* __restrict__ WT,
                                              int Kd, int Nd) {
  __shared__ float tile[64][65];
  const float* Wl = W + (size_t)blockIdx.z * Kd * Nd;
  ushort* WTl = WT + (size_t)blockIdx.z * Kd * Nd;
  int n0 = blockIdx.x * 64, k0 = blockIdx.y * 64;
  int tid = threadIdx.x;
  for (int e = tid; e < 64 * 64; e += 256) {
    int r = e >> 6, c = e & 63;
    tile[r][c] = Wl[(size_t)(k0 + r) * Nd + n0 + c];
  }
  __syncthreads();
  for (int e = tid; e < 64 * 64; e += 256) {
    int r = e >> 6, c = e & 63;
    WTl[(size_t)(n0 + r) * Kd + k0 + c] = f2bf(tile[c][r]);
  }
}

// ---------------- Gaussian edge features: ef[b,i,k] = sum_j (!pad_j) gauss ----
__global__ __launch_bounds__(128) void ef_kernel(
    const int* __restrict__ atoms, const float* __restrict__ pos,
    const float* __restrict__ means, const float* __restrict__ stds,
    const float* __restrict__ gmul, const float* __restrict__ gbias,
    float* __restrict__ ef) {
  int i = blockIdx.x, b = blockIdx.y;
  __shared__ float dist[Nn], ml[Nn], bs2[Nn];
  __shared__ int padm[Nn];
  int tid = threadIdx.x;
  int ai = atoms[b * Nn + i];
  float px = pos[(b * Nn + i) * 3], py = pos[(b * Nn + i) * 3 + 1], pz = pos[(b * Nn + i) * 3 + 2];
  for (int j = tid; j < Nn; j += 128) {
    int aj = atoms[b * Nn + j];
    float dx = px - pos[(b * Nn + j) * 3];
    float dy = py - pos[(b * Nn + j) * 3 + 1];
    float dz = pz - pos[(b * Nn + j) * 3 + 2];
    float sq = dx * dx + dy * dy + dz * dz;
    dist[j] = sq > 0.f ? sqrtf(sq) : 0.f;
    int et = ai * 10 + aj;
    ml[j] = gmul[et];
    bs2[j] = gbias[et];
    padm[j] = (aj == 0);
  }
  __syncthreads();
  int k = tid;
  float mean = means[k];
  float sd = fabsf(stds[k]) + 1e-5f;
  float inv = 1.0f / sd;
  float cn = 1.0f / (sqrtf(2.0f * 3.14159f) * sd);
  float acc = 0.f;
  for (int j = 0; j < Nn; ++j) {
    if (padm[j]) continue;
    float t = (ml[j] * dist[j] + bs2[j] - mean) * inv;
    acc += __expf(-0.5f * t * t);
  }
  ef[(b * Nn + i) * Kn + k] = acc * cn;
}

// ---------------- bias MLP, all-MFMA: one block per (b,i), 4 j-tiles ---------
__global__ __launch_bounds__(256) void gbias_kernel(
    const int* __restrict__ atoms, const float* __restrict__ pos,
    const float* __restrict__ means, const float* __restrict__ stds,
    const float* __restrict__ gmul, const float* __restrict__ gbias_,
    const ushort* __restrict__ w1T, const float* __restrict__ b1,
    const float* __restrict__ w2, const float* __restrict__ b2,
    ushort* __restrict__ biasb) {
  int i = blockIdx.x, b = blockIdx.y;
  __shared__ char W1s[32768];      // [128 n][128 k] bf16, XOR-swizzled; persists
  __shared__ char Ag[16384];       // phase B: gbf [64 j][128 k] / then g [64 j][128 n]
  __shared__ char W2s[4096];       // [16 h][128 n] bf16, XOR-swizzled (B-operand)
  __shared__ float b1s[128], invs_[128], mui[128], cns[128];
  __shared__ float dls[256], mll[256], bsl[256];
  __shared__ int pml[256];
  const int tid = threadIdx.x, w = tid >> 6, ln = tid & 63;
  const int frow = ln & 15, fgrp = ln >> 4;
  // stage W1T once (pre-swizzled source -> linear LDS; read side applies swizzle)
  {
    int srow = ln >> 4, sc = ln & 15;
#pragma unroll
    for (int q = 0; q < 8; ++q) {
      int inst = w * 8 + q;
      int row = inst * 4 + srow;
      const char* g = (const char*)(w1T + row * 128) + ((sc * 16) ^ ((row & 7) << 4));
      gload_lds16(g, W1s + inst * 1024);
    }
  }
  if (tid < 128) {
    float mean = means[tid];
    float sd = fabsf(stds[tid]) + 1e-5f;
    float inv = 1.0f / sd;
    invs_[tid] = inv;
    mui[tid] = mean * inv;
    cns[tid] = inv * 0.3989423f;  // 1/sqrt(2*3.14159) (matches ref constant)
    b1s[tid] = b1[tid];
  }
  // W2 as B-operand: [16 h][128 n] bf16 rows, swizzled; h>=12 rows zero
  for (int e = tid; e < 2048; e += 256) {
    int h = e >> 7, k = e & 127;
    float v = (h < 12) ? w2[k * 12 + h] : 0.f;
    *(ushort*)(W2s + h * 256 + ((2 * k) ^ ((h & 7) << 4))) = f2bf(v);
  }
  {
    int ai = atoms[b * Nn + i];
    int j = tid;
    int aj = atoms[b * Nn + j];
    float dx = pos[(b * Nn + i) * 3]     - pos[(b * Nn + j) * 3];
    float dy = pos[(b * Nn + i) * 3 + 1] - pos[(b * Nn + j) * 3 + 1];
    float dz = pos[(b * Nn + i) * 3 + 2] - pos[(b * Nn + j) * 3 + 2];
    float sq = dx * dx + dy * dy + dz * dz;
    dls[j] = sq > 0.f ? sqrtf(sq) : 0.f;
    int et = ai * 10 + aj;
    mll[j] = gmul[et];
    bsl[j] = gbias_[et];
    pml[j] = (aj == 0);
  }
  __syncthreads();

  for (int jt = 0; jt < 4; ++jt) {
    int j0 = jt * 64;
    // build Ag: gbf tile [64 j][128 k] bf16 swizzled.
    // thread (tid&127)=k, (tid>>7)=row-half; iterate 32 rows; hoist k-consts.
    {
      int k = tid & 127;
      float inv = invs_[k], mu = mui[k], cn = cns[k];
      int r0 = (tid >> 7) * 32;
#pragma unroll 4
      for (int rr = 0; rr < 32; ++rr) {
        int row = r0 + rr;
        int jj = j0 + row;
        float s = fmaf(mll[jj], dls[jj], bsl[jj]);
        float t = fmaf(inv, s, -mu);
        float g = __expf(-0.5f * t * t) * cn;
        *(ushort*)(Ag + row * 256 + ((2 * k) ^ ((row & 7) << 4))) = f2bf_t(g);
      }
    }
    __syncthreads();
    // phase B: [64,128]@[128,128] via MFMA; wave w owns j-rows w*16..+16
    f32x4 acc[8] = {};
    const int arow = w * 16 + frow;
#pragma unroll
    for (int ks = 0; ks < 4; ++ks) {
      bf16x8 af = *(const bf16x8*)(Ag + arow * 256 + ((ks * 64 + fgrp * 16) ^ ((arow & 7) << 4)));
#pragma unroll
      for (int nt = 0; nt < 8; ++nt) {
        int brow = nt * 16 + frow;
        bf16x8 bfv = *(const bf16x8*)(W1s + brow * 256 + ((ks * 64 + fgrp * 16) ^ ((brow & 7) << 4)));
        acc[nt] = MFMA16(af, bfv, acc[nt]);
      }
    }
    __syncthreads();  // Ag (gbf) reads done; reuse as g[j][n]
    // gelu + store g[j][n] bf16 swizzled (row-major j, A-operand-ready)
#pragma unroll
    for (int nt = 0; nt < 8; ++nt) {
      int n = nt * 16 + frow;
#pragma unroll
      for (int r = 0; r < 4; ++r) {
        int jloc = w * 16 + fgrp * 4 + r;
        float g = gelu_fast(acc[nt][r] + b1s[n]);
        *(ushort*)(Ag + jloc * 256 + ((2 * n) ^ ((jloc & 7) << 4))) = f2bf_t(g);
      }
    }
    __syncthreads();
    // phase C: [64,128]@[128,16] via MFMA -> out[j][h]
    {
      f32x4 acc2 = {};
      int jrow = w * 16 + frow;
#pragma unroll
      for (int ks = 0; ks < 4; ++ks) {
        bf16x8 af = *(const bf16x8*)(Ag + jrow * 256 + ((ks * 64 + fgrp * 16) ^ ((jrow & 7) << 4)));
        bf16x8 bfv = *(const bf16x8*)(W2s + frow * 256 + ((ks * 64 + fgrp * 16) ^ ((frow & 7) << 4)));
        acc2 = MFMA16(af, bfv, acc2);
      }
      if (frow < 12) {
        float bv = b2[frow];
#pragma unroll
        for (int r = 0; r < 4; ++r) {
          int jl = w * 16 + fgrp * 4 + r;
          int jg = j0 + jl;
          float v = pml[jg] ? NEGB : (acc2[r] + bv);
          biasb[(((size_t)b * Hn + frow) * Nn + i) * Nn + jg] = f2bf(v);
        }
      }
    }
    __syncthreads();  // before next jt overwrites Ag
  }
}

// ---------------- node = emb[atoms] + ef@edge_w + edge_b -> [N,B,D] bf16 ------
__global__ __launch_bounds__(256) void node_kernel(
    const int* __restrict__ atoms, const float* __restrict__ ef,
    const float* __restrict__ emb, const float* __restrict__ ew,
    const float* __restrict__ eb, ushort* __restrict__ nodeT) {
  int n = blockIdx.x, b = blockIdx.y;
  __shared__ float efs[Kn];
  int tid = threadIdx.x;
  if (tid < Kn) efs[tid] = ef[(b * Nn + n) * Kn + tid];
  __syncthreads();
  int a = atoms[b * Nn + n];
  for (int d = tid; d < Dn; d += 256) {
    float acc = emb[a * Dn + d] + eb[d];
#pragma unroll 8
    for (int k = 0; k < Kn; ++k) acc += efs[k] * ew[k * Dn + d];
    nodeT[(size_t)(n * Bn + b) * Dn + d] = f2bf(acc);
  }
}

// ---------------- MFMA GEMM 128x128 tile -------------------------------------
// MODE 0: bf16 out; 1: gelu bf16 out; 2: f32 out + residual; 3: f32 out
template <int MODE>
__global__ __launch_bounds__(256, 2) void mgemm128(
    const ushort* __restrict__ A, const ushort* __restrict__ WT,
    const float* __restrict__ bias, const float* __restrict__ res,
    void* __restrict__ Cout, int M, int Kd, int Nd) {
  __shared__ char smem[32768];
  char* ldsA = smem;
  char* ldsB = smem + 16384;
  const int tid = threadIdx.x, w = tid >> 6, ln = tid & 63;
  const int m0 = blockIdx.y * 128, n0 = blockIdx.x * 128;
  const int wm = (w >> 1) * 64, wn = (w & 1) * 64;
  const int srow = ln >> 3, schunk = ln & 7;
  const int sswz = (schunk * 16) ^ (srow << 4);
  const int frow = ln & 15, fgrp = ln >> 4;
  f32x4 acc[4][4] = {};
  for (int kt = 0; kt < Kd; kt += 64) {
    __syncthreads();
#pragma unroll
    for (int q = 0; q < 4; ++q) {
      int r = (w * 4 + q) * 8 + srow;
      gload_lds16((const char*)(A + (size_t)(m0 + r) * Kd + kt) + sswz, ldsA + (w * 4 + q) * 1024);
    }
#pragma unroll
    for (int q = 0; q < 4; ++q) {
      int r = (w * 4 + q) * 8 + srow;
      gload_lds16((const char*)(WT + (size_t)(n0 + r) * Kd + kt) + sswz, ldsB + (w * 4 + q) * 1024);
    }
    __syncthreads();
#pragma unroll
    for (int ks = 0; ks < 2; ++ks) {
      bf16x8 af[4], bfv[4];
#pragma unroll
      for (int mt = 0; mt < 4; ++mt) {
        int row = wm + mt * 16 + frow;
        af[mt] = *(const bf16x8*)(ldsA + row * 128 + ((ks * 64 + fgrp * 16) ^ ((row & 7) << 4)));
      }
#pragma unroll
      for (int nt = 0; nt < 4; ++nt) {
        int row = wn + nt * 16 + frow;
        bfv[nt] = *(const bf16x8*)(ldsB + row * 128 + ((ks * 64 + fgrp * 16) ^ ((row & 7) << 4)));
      }
#pragma unroll
      for (int mt = 0; mt < 4; ++mt)
#pragma unroll
        for (int nt = 0; nt < 4; ++nt)
          acc[mt][nt] = MFMA16(af[mt], bfv[nt], acc[mt][nt]);
    }
  }
#pragma unroll
  for (int nt = 0; nt < 4; ++nt) {
    int n = n0 + wn + nt * 16 + frow;
    float bv = bias[n];
#pragma unroll
    for (int mt = 0; mt < 4; ++mt) {
#pragma unroll
      for (int r = 0; r < 4; ++r) {
        int m = m0 + wm + mt * 16 + fgrp * 4 + r;
        float v = acc[mt][nt][r] + bv;
        if (MODE == 1) v = gelu_fast(v);
        if (MODE == 2) v += res[(size_t)m * Nd + n];
        if (MODE <= 1) ((ushort*)Cout)[(size_t)m * Nd + n] = f2bf(v);
        else           ((float*)Cout)[(size_t)m * Nd + n] = v;
      }
    }
  }
}

// ---------------- per-layer V transpose: qkv V section -> vT[b,h,d,j] bf16 ----
__global__ __launch_bounds__(256) void vtrans(const ushort* __restrict__ qkvb,
                                              ushort* __restrict__ vT) {
  int h = blockIdx.x, b = blockIdx.y;
  __shared__ ushort Vs[256][64];
  int tid = threadIdx.x;
  for (int idx = tid; idx < 2048; idx += 256) {
    int j = idx >> 3, ch = idx & 7;
    *(bf16x8*)&Vs[j][ch * 8] =
        *(const bf16x8*)(qkvb + (size_t)(j * 8 + b) * 2304 + 1536 + h * 64 + ch * 8);
  }
  __syncthreads();
  char* base = (char*)(vT + (size_t)((b * Hn + h) * 64) * 256);
  for (int idx = tid; idx < 2048; idx += 256) {
    int d = idx & 63, jc = idx >> 6;
    ushort tmp[8];
#pragma unroll
    for (int jj = 0; jj < 8; ++jj) tmp[jj] = Vs[jc * 8 + jj][d];
    *(bf16x8*)(base + d * 512 + jc * 16) = *(bf16x8*)tmp;
  }
}

// ---------------- MFMA attention: block = (b, h, 64 i-rows) -------------------
__global__ __launch_bounds__(256, 2) void attn_mfma(
    const ushort* __restrict__ qkv, const ushort* __restrict__ vT,
    const ushort* __restrict__ biasb, ushort* __restrict__ Oout) {
  int it = blockIdx.x, h = blockIdx.y, b = blockIdx.z;
  int i0 = it * 64;
  __shared__ char smem[65536];
  char* Ks = smem;           // [256 j][64 k] bf16 swizzled; later P[4][16][256]
  char* Vs = smem + 32768;   // [64 d][256 j] bf16 swizzled (V^T)
  const int tid = threadIdx.x, w = tid >> 6, ln = tid & 63;
  const int frow = ln & 15, fgrp = ln >> 4;
  // stage K
  {
    const int srow = ln >> 3, schunk = ln & 7;
#pragma unroll
    for (int q = 0; q < 8; ++q) {
      int inst = w * 8 + q;
      int row = inst * 8 + srow;  // j
      const char* g = (const char*)(qkv + (size_t)(row * 8 + b) * 2304 + 768 + h * 64) +
                      ((schunk * 16) ^ ((row & 7) << 4));
      gload_lds16(g, Ks + inst * 1024);
    }
    // stage V^T (rows d, 512B)
#pragma unroll
    for (int q = 0; q < 8; ++q) {
      int inst = w * 8 + q;
      int row = inst * 2 + (ln >> 5);
      int cb = (ln & 31) * 16;
      const char* g = (const char*)(vT + (size_t)((b * Hn + h) * 64 + row) * 256) +
                      (cb ^ ((row & 7) << 4));
      gload_lds16(g, Vs + inst * 1024);
    }
  }
  // Q fragments from global
  bf16x8 qf[2];
  {
    int qrow = i0 + w * 16 + frow;
    const ushort* qg = qkv + (size_t)(qrow * 8 + b) * 2304 + h * 64 + fgrp * 8;
    qf[0] = *(const bf16x8*)qg;
    qf[1] = *(const bf16x8*)(qg + 32);
  }
  __syncthreads();
  // QK^T
  f32x4 s[16];
#pragma unroll
  for (int jtl = 0; jtl < 16; ++jtl) {
    int row = jtl * 16 + frow;
    const char* kb = Ks + row * 128;
    bf16x8 k0 = *(const bf16x8*)(kb + ((fgrp * 16) ^ ((row & 7) << 4)));
    bf16x8 k1 = *(const bf16x8*)(kb + ((64 + fgrp * 16) ^ ((row & 7) << 4)));
    f32x4 t = {};
    t = MFMA16(qf[0], k0, t);
    t = MFMA16(qf[1], k1, t);
    s[jtl] = t;
  }
  // bias + scale + softmax (rows fgrp*4+r, cols frow+16*jtl)
  float inv[4];
#pragma unroll
  for (int r = 0; r < 4; ++r) {
    int i = i0 + w * 16 + fgrp * 4 + r;
    const ushort* brow = biasb + (((size_t)b * Hn + h) * Nn + i) * Nn;
    float m = -3.0e38f;
#pragma unroll
    for (int jtl = 0; jtl < 16; ++jtl) {
      float v = s[jtl][r] * SCALE + bf2f(brow[jtl * 16 + frow]);
      s[jtl][r] = v;
      m = fmaxf(m, v);
    }
    m = fmaxf(m, __shfl_xor(m, 1)); m = fmaxf(m, __shfl_xor(m, 2));
    m = fmaxf(m, __shfl_xor(m, 4)); m = fmaxf(m, __shfl_xor(m, 8));
    float su = 0.f;
#pragma unroll
    for (int jtl = 0; jtl < 16; ++jtl) {
      float p = __expf(s[jtl][r] - m);
      s[jtl][r] = p;
      su += p;
    }
    su += __shfl_xor(su, 1); su += __shfl_xor(su, 2);
    su += __shfl_xor(su, 4); su += __shfl_xor(su, 8);
    inv[r] = 1.0f / su;
  }
  __syncthreads();  // all waves done reading Ks
  // write P (unnormalized) into Ks region, per-wave [16][256] bf16 swizzled
  char* Ps = Ks + w * 8192;
#pragma unroll
  for (int r = 0; r < 4; ++r) {
    int prow = fgrp * 4 + r;
#pragma unroll
    for (int jtl = 0; jtl < 16; ++jtl) {
      int cb = jtl * 32 + frow * 2;
      *(ushort*)(Ps + prow * 512 + (cb ^ ((prow & 7) << 4))) = f2bf_t(s[jtl][r]);
    }
  }
  __syncthreads();
  // PV
  bf16x8 pf[8];
#pragma unroll
  for (int ks = 0; ks < 8; ++ks)
    pf[ks] = *(const bf16x8*)(Ps + frow * 512 + ((ks * 64 + fgrp * 16) ^ ((frow & 7) << 4)));
  f32x4 o[4] = {};
#pragma unroll
  for (int dt = 0; dt < 4; ++dt) {
#pragma unroll
    for (int ks = 0; ks < 8; ++ks) {
      int row = dt * 16 + frow;
      bf16x8 vf = *(const bf16x8*)(Vs + row * 512 + ((ks * 64 + fgrp * 16) ^ ((row & 7) << 4)));
      o[dt] = MFMA16(pf[ks], vf, o[dt]);
    }
  }
#pragma unroll
  for (int dt = 0; dt < 4; ++dt)
#pragma unroll
    for (int r = 0; r < 4; ++r) {
      int i = i0 + w * 16 + fgrp * 4 + r;
      Oout[(size_t)(i * 8 + b) * Dn + h * 64 + dt * 16 + frow] = f2bf(o[dt][r] * inv[r]);
    }
}

// ---------------- LayerNorm over D=768 ---------------------------------------
// MODE 0: bf16 out [T][D]; MODE 1: f32 out transposed to [B,N,D]
template <int MODE>
__global__ __launch_bounds__(256) void ln_kernel(
    const float* __restrict__ x, const float* __restrict__ sc,
    const float* __restrict__ bi, void* __restrict__ out) {
  int t = blockIdx.x;
  int tid = threadIdx.x;
  const float* xr = x + (size_t)t * Dn;
  float v0 = xr[tid], v1 = xr[tid + 256], v2 = xr[tid + 512];
  __shared__ float red[4], red2[4];
  float s = wave_sum(v0 + v1 + v2);
  if ((tid & 63) == 0) red[tid >> 6] = s;
  __syncthreads();
  float mean = (red[0] + red[1] + red[2] + red[3]) * (1.0f / 768.0f);
  float d0 = v0 - mean, d1 = v1 - mean, d2 = v2 - mean;
  float vs = wave_sum(d0 * d0 + d1 * d1 + d2 * d2);
  if ((tid & 63) == 0) red2[tid >> 6] = vs;
  __syncthreads();
  float var = (red2[0] + red2[1] + red2[2] + red2[3]) * (1.0f / 768.0f);
  float r = rsqrtf(var + 1e-5f);
  if (MODE == 0) {
    ushort* o = (ushort*)out + (size_t)t * Dn;
    o[tid]       = f2bf(d0 * r * sc[tid]       + bi[tid]);
    o[tid + 256] = f2bf(d1 * r * sc[tid + 256] + bi[tid + 256]);
    o[tid + 512] = f2bf(d2 * r * sc[tid + 512] + bi[tid + 512]);
  } else {
    int n = t >> 3, bb = t & 7;
    float* o = (float*)out + (size_t)(bb * Nn + n) * Dn;
    o[tid]       = d0 * r * sc[tid]       + bi[tid];
    o[tid + 256] = d1 * r * sc[tid + 256] + bi[tid + 256];
    o[tid + 512] = d2 * r * sc[tid + 512] + bi[tid + 512];
  }
}

// =============================================================================
extern "C" void kernel_launch(void* const* d_in, const int* in_sizes, int n_in,
                              void* d_out, int out_size, void* d_ws, size_t ws_size,
                              hipStream_t stream) {
  (void)in_sizes; (void)n_in; (void)out_size; (void)ws_size;
  const int*   atoms    = (const int*)  d_in[0];
  const float* pos      = (const float*)d_in[1];
  const float* atom_emb = (const float*)d_in[2];
  const float* gbf_means= (const float*)d_in[3];
  const float* gbf_stds = (const float*)d_in[4];
  const float* gbf_mul  = (const float*)d_in[5];
  const float* gbf_bias = (const float*)d_in[6];
  const float* bp_w1    = (const float*)d_in[7];
  const float* bp_b1    = (const float*)d_in[8];
  const float* bp_w2    = (const float*)d_in[9];
  const float* bp_b2    = (const float*)d_in[10];
  const float* edge_w   = (const float*)d_in[11];
  const float* edge_b   = (const float*)d_in[12];
  const float* ap_w     = (const float*)d_in[13];
  const float* ap_b     = (const float*)d_in[14];
  const float* ln1_s    = (const float*)d_in[15];
  const float* ln1_b    = (const float*)d_in[16];
  const float* wi       = (const float*)d_in[17];
  const float* bi       = (const float*)d_in[18];
  const float* wo       = (const float*)d_in[19];
  const float* bo       = (const float*)d_in[20];
  const float* ln2_s    = (const float*)d_in[21];
  const float* ln2_b    = (const float*)d_in[22];
  const float* w1       = (const float*)d_in[23];
  const float* b1       = (const float*)d_in[24];
  const float* w2       = (const float*)d_in[25];
  const float* b2       = (const float*)d_in[26];
  const float* fln_s    = (const float*)d_in[27];
  const float* fln_b    = (const float*)d_in[28];
  float* out = (float*)d_out;

  // workspace layout (u16 units unless noted)
  ushort* wsb   = (ushort*)d_ws;
  ushort* biasb = wsb;                                  // 6291456
  ushort* qkvb  = biasb + (size_t)Bn * Hn * Nn * Nn;    // 4718592 (also ffn mid, also apT)
  ushort* hb    = qkvb + (size_t)Tn * 2304;             // 1572864
  ushort* vT    = hb + (size_t)Tn * Dn;                 // 1572864 (efb overlays start)
  ushort* wiT   = vT + (size_t)Bn * Hn * 64 * 256;      // 7077888
  ushort* woT   = wiT + (size_t)4 * 2304 * Dn;          // 2359296
  ushort* w1T   = woT + (size_t)4 * Dn * Dn;            // 2359296
  ushort* w2T   = w1T + (size_t)4 * Dn * Dn;            // 2359296
  ushort* w1bT  = w2T + (size_t)4 * Dn * Dn;            // 16384
  float*  xbuf  = (float*)(w1bT + 16384);               // Tn*Dn f32
  ushort* apT   = qkvb;                                 // overlay (dead before qkv GEMM)
  ushort* ffnb  = qkvb;                                 // overlay (qkv dead in FFN phase)
  float*  efb   = (float*)vT;                           // overlay (dead before layer 0)

  // weight prep
  wtrans<<<dim3(12, 12, 1), 256, 0, stream>>>(ap_w, apT, 768, 768);
  wtrans<<<dim3(36, 12, 4), 256, 0, stream>>>(wi, wiT, 768, 2304);
  wtrans<<<dim3(12, 12, 4), 256, 0, stream>>>(wo, woT, 768, 768);
  wtrans<<<dim3(12, 12, 4), 256, 0, stream>>>(w1, w1T, 768, 768);
  wtrans<<<dim3(12, 12, 4), 256, 0, stream>>>(w2, w2T, 768, 768);
  wtrans<<<dim3(2, 2, 1), 256, 0, stream>>>(bp_w1, w1bT, 128, 128);

  dim3 gridNB(Nn, Bn);
  ef_kernel<<<gridNB, 128, 0, stream>>>(atoms, pos, gbf_means, gbf_stds, gbf_mul, gbf_bias, efb);
  gbias_kernel<<<gridNB, 256, 0, stream>>>(atoms, pos, gbf_means, gbf_stds,
                                           gbf_mul, gbf_bias, w1bT, bp_b1, bp_w2, bp_b2, biasb);
  node_kernel<<<gridNB, 256, 0, stream>>>(atoms, efb, atom_emb, edge_w, edge_b, hb);
  mgemm128<3><<<dim3(6, 16), 256, 0, stream>>>(hb, apT, ap_b, nullptr, xbuf, Tn, Dn, Dn);

  for (int it = 0; it < 8; ++it) {
    int l = it & 3;
    ln_kernel<0><<<Tn, 256, 0, stream>>>(xbuf, ln1_s + l * Dn, ln1_b + l * Dn, hb);
    mgemm128<0><<<dim3(18, 16), 256, 0, stream>>>(hb, wiT + (size_t)l * 2304 * Dn,
                                                  bi + l * 2304, nullptr, qkvb, Tn, Dn, 2304);
    vtrans<<<dim3(Hn, Bn), 256, 0, stream>>>(qkvb, vT);
    attn_mfma<<<dim3(4, Hn, Bn), 256, 0, stream>>>(qkvb, vT, biasb, hb);
    mgemm128<2><<<dim3(6, 16), 256, 0, stream>>>(hb, woT + (size_t)l * Dn * Dn,
                                                 bo + l * Dn, xbuf, xbuf, Tn, Dn, Dn);
    ln_kernel<0><<<Tn, 256, 0, stream>>>(xbuf, ln2_s + l * Dn, ln2_b + l * Dn, hb);
    mgemm128<1><<<dim3(6, 16), 256, 0, stream>>>(hb, w1T + (size_t)l * Dn * Dn,
                                                 b1 + l * Dn, nullptr, ffnb, Tn, Dn, Dn);
    mgemm128<2><<<dim3(6, 16), 256, 0, stream>>>(ffnb, w2T + (size_t)l * Dn * Dn,
                                                 b2 + l * Dn, xbuf, xbuf, Tn, Dn, Dn);
  }
  ln_kernel<1><<<Tn, 256, 0, stream>>>(xbuf, fln_s, fln_b, out);
}

// Round 6
// 877.756 us; speedup vs baseline: 1.3036x; 1.3036x over previous
//
#include <hip/hip_runtime.h>
#include <math.h>

constexpr int Bn = 8, Nn = 256, Dn = 768, Hn = 12, Kn = 128;
constexpr int Tn = Nn * Bn;      // 2048 tokens
constexpr float SCALE = 0.125f;  // HD^-0.5, HD=64
constexpr float NEGB = -1e9f;

typedef __attribute__((ext_vector_type(8))) short bf16x8;
typedef __attribute__((ext_vector_type(4))) float f32x4;

#define MFMA16(a, b, c) __builtin_amdgcn_mfma_f32_16x16x32_bf16((a), (b), (c), 0, 0, 0)

__device__ __forceinline__ void gload_lds16(const void* g, void* l) {
  __builtin_amdgcn_global_load_lds(
      (const __attribute__((address_space(1))) void*)g,
      (__attribute__((address_space(3))) void*)l, 16, 0, 0);
}

__device__ __forceinline__ ushort f2bf(float x) {  // round-to-nearest-even
  union { float f; unsigned u; } v; v.f = x;
  unsigned r = (v.u + 0x7fff + ((v.u >> 16) & 1)) >> 16;
  return (ushort)r;
}
__device__ __forceinline__ ushort f2bf_t(float x) {  // truncate (1 inst)
  union { float f; unsigned u; } v; v.f = x;
  return (ushort)(v.u >> 16);
}
__device__ __forceinline__ float bf2f(ushort u) {
  union { unsigned u; float f; } v; v.u = ((unsigned)u) << 16;
  return v.f;
}
// tanh-approx gelu (|err| <~3e-3)
__device__ __forceinline__ float gelu_fast(float x) {
  float u = x * (0.7978845608f + 0.0356774081f * x * x);
  float e = __expf(2.0f * u);
  float t = 1.0f - 2.0f / (e + 1.0f);
  return 0.5f * x * (1.0f + t);
}
__device__ __forceinline__ float wave_sum(float v) {
#pragma unroll
  for (int off = 32; off; off >>= 1) v += __shfl_xor(v, off);
  return v;
}

// ---------------- weight transpose+convert: W[K,N] f32 -> WT[N,K] bf16 -------
__global__ __launch_bounds__(256) void wtrans(const float* __restrict__ W,
                                              ushort* __restrict__ WT,
                                              int Kd, int Nd) {
  __shared__ float tile[64][65];
  const float* Wl = W + (size_t)blockIdx.z * Kd * Nd;
  ushort* WTl = WT + (size_t)blockIdx.z * Kd * Nd;
  int n0 = blockIdx.x * 64, k0 = blockIdx.y * 64;
  int tid = threadIdx.x;
  for (int e = tid; e < 64 * 64; e += 256) {
    int r = e >> 6, c = e & 63;
    tile[r][c] = Wl[(size_t)(k0 + r) * Nd + n0 + c];
  }
  __syncthreads();
  for (int e = tid; e < 64 * 64; e += 256) {
    int r = e >> 6, c = e & 63;
    WTl[(size_t)(n0 + r) * Kd + k0 + c] = f2bf(tile[c][r]);
  }
}

// ---------------- Gaussian edge features: ef[b,i,k] = sum_j (!pad_j) gauss ----
__global__ __launch_bounds__(128) void ef_kernel(
    const int* __restrict__ atoms, const float* __restrict__ pos,
    const float* __restrict__ means, const float* __restrict__ stds,
    const float* __restrict__ gmul, const float* __restrict__ gbias,
    float* __restrict__ ef) {
  int i = blockIdx.x, b = blockIdx.y;
  __shared__ float dist[Nn], ml[Nn], bs2[Nn];
  __shared__ int padm[Nn];
  int tid = threadIdx.x;
  int ai = atoms[b * Nn + i];
  float px = pos[(b * Nn + i) * 3], py = pos[(b * Nn + i) * 3 + 1], pz = pos[(b * Nn + i) * 3 + 2];
  for (int j = tid; j < Nn; j += 128) {
    int aj = atoms[b * Nn + j];
    float dx = px - pos[(b * Nn + j) * 3];
    float dy = py - pos[(b * Nn + j) * 3 + 1];
    float dz = pz - pos[(b * Nn + j) * 3 + 2];
    float sq = dx * dx + dy * dy + dz * dz;
    dist[j] = sq > 0.f ? sqrtf(sq) : 0.f;
    int et = ai * 10 + aj;
    ml[j] = gmul[et];
    bs2[j] = gbias[et];
    padm[j] = (aj == 0);
  }
  __syncthreads();
  int k = tid;
  float mean = means[k];
  float sd = fabsf(stds[k]) + 1e-5f;
  float inv = 1.0f / sd;
  float cn = 1.0f / (sqrtf(2.0f * 3.14159f) * sd);
  float acc = 0.f;
  for (int j = 0; j < Nn; ++j) {
    if (padm[j]) continue;
    float t = (ml[j] * dist[j] + bs2[j] - mean) * inv;
    acc += __expf(-0.5f * t * t);
  }
  ef[(b * Nn + i) * Kn + k] = acc * cn;
}

// ---------------- bias MLP, all-MFMA, W1 in registers ------------------------
__global__ __launch_bounds__(256) void gbias_kernel(
    const int* __restrict__ atoms, const float* __restrict__ pos,
    const float* __restrict__ means, const float* __restrict__ stds,
    const float* __restrict__ gmul, const float* __restrict__ gbias_,
    const ushort* __restrict__ w1T, const float* __restrict__ b1,
    const float* __restrict__ w2, const float* __restrict__ b2,
    ushort* __restrict__ biasb) {
  int i = blockIdx.x, b = blockIdx.y;
  __shared__ char Ag[16384];       // phase B: gbf [64 j][128 k] swz / then g [64 j][128 n]
  __shared__ char W2s[4096];       // [16 h][128 n] bf16, XOR-swizzled (B-operand)
  __shared__ float sj[256];        // ml*dist+bs per j
  __shared__ int pml[256];
  __shared__ float b1s[128], invs_[128], mui[128], cns[128];
  const int tid = threadIdx.x, w = tid >> 6, ln = tid & 63;
  const int frow = ln & 15, fgrp = ln >> 4;
  // W1 fragments -> registers (once per block; L2-resident after first blocks)
  bf16x8 wf[4][8];
#pragma unroll
  for (int ks = 0; ks < 4; ++ks)
#pragma unroll
    for (int nt = 0; nt < 8; ++nt)
      wf[ks][nt] = *(const bf16x8*)(w1T + (nt * 16 + frow) * 128 + ks * 32 + fgrp * 8);
  if (tid < 128) {
    float mean = means[tid];
    float sd = fabsf(stds[tid]) + 1e-5f;
    float inv = 1.0f / sd;
    invs_[tid] = inv;
    mui[tid] = mean * inv;
    cns[tid] = inv * 0.3989423f;  // 1/sqrt(2*3.14159)
    b1s[tid] = b1[tid];
  }
  // W2 as B-operand: [16 h][128 n] bf16 rows, swizzled; h>=12 rows zero
  for (int e = tid; e < 2048; e += 256) {
    int h = e >> 7, k = e & 127;
    float v = (h < 12) ? w2[k * 12 + h] : 0.f;
    *(ushort*)(W2s + h * 256 + ((2 * k) ^ ((h & 7) << 4))) = f2bf(v);
  }
  {
    int ai = atoms[b * Nn + i];
    int j = tid;
    int aj = atoms[b * Nn + j];
    float dx = pos[(b * Nn + i) * 3]     - pos[(b * Nn + j) * 3];
    float dy = pos[(b * Nn + i) * 3 + 1] - pos[(b * Nn + j) * 3 + 1];
    float dz = pos[(b * Nn + i) * 3 + 2] - pos[(b * Nn + j) * 3 + 2];
    float sq = dx * dx + dy * dy + dz * dz;
    float d = sq > 0.f ? sqrtf(sq) : 0.f;
    int et = ai * 10 + aj;
    sj[j] = fmaf(gmul[et], d, gbias_[et]);
    pml[j] = (aj == 0);
  }
  __syncthreads();

  for (int jt = 0; jt < 4; ++jt) {
    int j0 = jt * 64;
    // build Ag: gbf tile [64 j][128 k] bf16 swizzled; thread k = tid&127
    {
      int k = tid & 127;
      float inv = invs_[k], mu = mui[k], cn = cns[k];
      int r0 = (tid >> 7) * 32;
#pragma unroll 8
      for (int rr = 0; rr < 32; ++rr) {
        int row = r0 + rr;
        float t = fmaf(inv, sj[j0 + row], -mu);
        float g = __expf(-0.5f * t * t) * cn;
        *(ushort*)(Ag + row * 256 + ((2 * k) ^ ((row & 7) << 4))) = f2bf_t(g);
      }
    }
    __syncthreads();
    // phase B: [64,128]@[128,128]; wave w owns j-rows w*16..+16; B from regs
    f32x4 acc[8] = {};
    const int arow = w * 16 + frow;
#pragma unroll
    for (int ks = 0; ks < 4; ++ks) {
      bf16x8 af = *(const bf16x8*)(Ag + arow * 256 + ((ks * 64 + fgrp * 16) ^ ((arow & 7) << 4)));
#pragma unroll
      for (int nt = 0; nt < 8; ++nt)
        acc[nt] = MFMA16(af, wf[ks][nt], acc[nt]);
    }
    __syncthreads();  // Ag (gbf) reads done; reuse as g[j][n]
    // gelu + store g[j][n] bf16 swizzled (A-operand-ready)
#pragma unroll
    for (int nt = 0; nt < 8; ++nt) {
      int n = nt * 16 + frow;
#pragma unroll
      for (int r = 0; r < 4; ++r) {
        int jloc = w * 16 + fgrp * 4 + r;
        float g = gelu_fast(acc[nt][r] + b1s[n]);
        *(ushort*)(Ag + jloc * 256 + ((2 * n) ^ ((jloc & 7) << 4))) = f2bf_t(g);
      }
    }
    __syncthreads();
    // phase C: [64,128]@[128,16] via MFMA -> out[j][h]
    {
      f32x4 acc2 = {};
      int jrow = w * 16 + frow;
#pragma unroll
      for (int ks = 0; ks < 4; ++ks) {
        bf16x8 af = *(const bf16x8*)(Ag + jrow * 256 + ((ks * 64 + fgrp * 16) ^ ((jrow & 7) << 4)));
        bf16x8 bfv = *(const bf16x8*)(W2s + frow * 256 + ((ks * 64 + fgrp * 16) ^ ((frow & 7) << 4)));
        acc2 = MFMA16(af, bfv, acc2);
      }
      if (frow < 12) {
        float bv = b2[frow];
#pragma unroll
        for (int r = 0; r < 4; ++r) {
          int jl = w * 16 + fgrp * 4 + r;
          int jg = j0 + jl;
          float v = pml[jg] ? NEGB : (acc2[r] + bv);
          biasb[(((size_t)b * Hn + frow) * Nn + i) * Nn + jg] = f2bf(v);
        }
      }
    }
    __syncthreads();  // before next jt overwrites Ag
  }
}

// ---------------- node = emb[atoms] + ef@edge_w + edge_b -> [N,B,D] bf16 ------
__global__ __launch_bounds__(256) void node_kernel(
    const int* __restrict__ atoms, const float* __restrict__ ef,
    const float* __restrict__ emb, const float* __restrict__ ew,
    const float* __restrict__ eb, ushort* __restrict__ nodeT) {
  int n = blockIdx.x, b = blockIdx.y;
  __shared__ float efs[Kn];
  int tid = threadIdx.x;
  if (tid < Kn) efs[tid] = ef[(b * Nn + n) * Kn + tid];
  __syncthreads();
  int a = atoms[b * Nn + n];
  for (int d = tid; d < Dn; d += 256) {
    float acc = emb[a * Dn + d] + eb[d];
#pragma unroll 8
    for (int k = 0; k < Kn; ++k) acc += efs[k] * ew[k * Dn + d];
    nodeT[(size_t)(n * Bn + b) * Dn + d] = f2bf(acc);
  }
}

// ---------------- MFMA GEMM 64x64 tile (for N=768 GEMMs; 384-block grid) -----
// MODE 0: bf16 out; 1: gelu bf16 out; 2: f32 out + residual; 3: f32 out
template <int MODE>
__global__ __launch_bounds__(256, 4) void mgemm(
    const ushort* __restrict__ A, const ushort* __restrict__ WT,
    const float* __restrict__ bias, const float* __restrict__ res,
    void* __restrict__ Cout, int M, int Kd, int Nd) {
  __shared__ char smem[16384];
  char* ldsA = smem;
  char* ldsB = smem + 8192;
  const int tid = threadIdx.x, w = tid >> 6, ln = tid & 63;
  const int m0 = blockIdx.y * 64, n0 = blockIdx.x * 64;
  const int wm = (w >> 1) * 32, wn = (w & 1) * 32;
  const int srow = ln >> 3, schunk = ln & 7;
  const int sswz = (schunk * 16) ^ (srow << 4);
  const int frow = ln & 15, fgrp = ln >> 4;
  f32x4 acc[2][2] = {};
  for (int kt = 0; kt < Kd; kt += 64) {
    __syncthreads();
#pragma unroll
    for (int q = 0; q < 2; ++q) {
      int r = (w * 2 + q) * 8 + srow;
      gload_lds16((const char*)(A + (size_t)(m0 + r) * Kd + kt) + sswz, ldsA + (w * 2 + q) * 1024);
    }
#pragma unroll
    for (int q = 0; q < 2; ++q) {
      int r = (w * 2 + q) * 8 + srow;
      gload_lds16((const char*)(WT + (size_t)(n0 + r) * Kd + kt) + sswz, ldsB + (w * 2 + q) * 1024);
    }
    __syncthreads();
#pragma unroll
    for (int ks = 0; ks < 2; ++ks) {
      bf16x8 af[2], bfv[2];
#pragma unroll
      for (int mt = 0; mt < 2; ++mt) {
        int row = wm + mt * 16 + frow;
        af[mt] = *(const bf16x8*)(ldsA + row * 128 + ((ks * 64 + fgrp * 16) ^ ((row & 7) << 4)));
      }
#pragma unroll
      for (int nt = 0; nt < 2; ++nt) {
        int row = wn + nt * 16 + frow;
        bfv[nt] = *(const bf16x8*)(ldsB + row * 128 + ((ks * 64 + fgrp * 16) ^ ((row & 7) << 4)));
      }
      acc[0][0] = MFMA16(af[0], bfv[0], acc[0][0]);
      acc[0][1] = MFMA16(af[0], bfv[1], acc[0][1]);
      acc[1][0] = MFMA16(af[1], bfv[0], acc[1][0]);
      acc[1][1] = MFMA16(af[1], bfv[1], acc[1][1]);
    }
  }
#pragma unroll
  for (int nt = 0; nt < 2; ++nt) {
    int n = n0 + wn + nt * 16 + frow;
    float bv = bias[n];
#pragma unroll
    for (int mt = 0; mt < 2; ++mt) {
#pragma unroll
      for (int r = 0; r < 4; ++r) {
        int m = m0 + wm + mt * 16 + fgrp * 4 + r;
        float v = acc[mt][nt][r] + bv;
        if (MODE == 1) v = gelu_fast(v);
        if (MODE == 2) v += res[(size_t)m * Nd + n];
        if (MODE <= 1) ((ushort*)Cout)[(size_t)m * Nd + n] = f2bf(v);
        else           ((float*)Cout)[(size_t)m * Nd + n] = v;
      }
    }
  }
}

// ---------------- MFMA GEMM 128x128 tile (qkv GEMM, 288-block grid) ----------
template <int MODE>
__global__ __launch_bounds__(256, 2) void mgemm128(
    const ushort* __restrict__ A, const ushort* __restrict__ WT,
    const float* __restrict__ bias, const float* __restrict__ res,
    void* __restrict__ Cout, int M, int Kd, int Nd) {
  __shared__ char smem[32768];
  char* ldsA = smem;
  char* ldsB = smem + 16384;
  const int tid = threadIdx.x, w = tid >> 6, ln = tid & 63;
  const int m0 = blockIdx.y * 128, n0 = blockIdx.x * 128;
  const int wm = (w >> 1) * 64, wn = (w & 1) * 64;
  const int srow = ln >> 3, schunk = ln & 7;
  const int sswz = (schunk * 16) ^ (srow << 4);
  const int frow = ln & 15, fgrp = ln >> 4;
  f32x4 acc[4][4] = {};
  for (int kt = 0; kt < Kd; kt += 64) {
    __syncthreads();
#pragma unroll
    for (int q = 0; q < 4; ++q) {
      int r = (w * 4 + q) * 8 + srow;
      gload_lds16((const char*)(A + (size_t)(m0 + r) * Kd + kt) + sswz, ldsA + (w * 4 + q) * 1024);
    }
#pragma unroll
    for (int q = 0; q < 4; ++q) {
      int r = (w * 4 + q) * 8 + srow;
      gload_lds16((const char*)(WT + (size_t)(n0 + r) * Kd + kt) + sswz, ldsB + (w * 4 + q) * 1024);
    }
    __syncthreads();
#pragma unroll
    for (int ks = 0; ks < 2; ++ks) {
      bf16x8 af[4], bfv[4];
#pragma unroll
      for (int mt = 0; mt < 4; ++mt) {
        int row = wm + mt * 16 + frow;
        af[mt] = *(const bf16x8*)(ldsA + row * 128 + ((ks * 64 + fgrp * 16) ^ ((row & 7) << 4)));
      }
#pragma unroll
      for (int nt = 0; nt < 4; ++nt) {
        int row = wn + nt * 16 + frow;
        bfv[nt] = *(const bf16x8*)(ldsB + row * 128 + ((ks * 64 + fgrp * 16) ^ ((row & 7) << 4)));
      }
#pragma unroll
      for (int mt = 0; mt < 4; ++mt)
#pragma unroll
        for (int nt = 0; nt < 4; ++nt)
          acc[mt][nt] = MFMA16(af[mt], bfv[nt], acc[mt][nt]);
    }
  }
#pragma unroll
  for (int nt = 0; nt < 4; ++nt) {
    int n = n0 + wn + nt * 16 + frow;
    float bv = bias[n];
#pragma unroll
    for (int mt = 0; mt < 4; ++mt) {
#pragma unroll
      for (int r = 0; r < 4; ++r) {
        int m = m0 + wm + mt * 16 + fgrp * 4 + r;
        float v = acc[mt][nt][r] + bv;
        if (MODE == 1) v = gelu_fast(v);
        if (MODE == 2) v += res[(size_t)m * Nd + n];
        if (MODE <= 1) ((ushort*)Cout)[(size_t)m * Nd + n] = f2bf(v);
        else           ((float*)Cout)[(size_t)m * Nd + n] = v;
      }
    }
  }
}

// ---------------- per-layer V transpose: qkv V section -> vT[b,h,d,j] bf16 ----
__global__ __launch_bounds__(256) void vtrans(const ushort* __restrict__ qkvb,
                                              ushort* __restrict__ vT) {
  int h = blockIdx.x, b = blockIdx.y;
  __shared__ ushort Vs[256][64];
  int tid = threadIdx.x;
  for (int idx = tid; idx < 2048; idx += 256) {
    int j = idx >> 3, ch = idx & 7;
    *(bf16x8*)&Vs[j][ch * 8] =
        *(const bf16x8*)(qkvb + (size_t)(j * 8 + b) * 2304 + 1536 + h * 64 + ch * 8);
  }
  __syncthreads();
  char* base = (char*)(vT + (size_t)((b * Hn + h) * 64) * 256);
  for (int idx = tid; idx < 2048; idx += 256) {
    int d = idx & 63, jc = idx >> 6;
    ushort tmp[8];
#pragma unroll
    for (int jj = 0; jj < 8; ++jj) tmp[jj] = Vs[jc * 8 + jj][d];
    *(bf16x8*)(base + d * 512 + jc * 16) = *(bf16x8*)tmp;
  }
}

// ---------------- MFMA attention: block = (b, h, 64 i-rows) -------------------
__global__ __launch_bounds__(256, 2) void attn_mfma(
    const ushort* __restrict__ qkv, const ushort* __restrict__ vT,
    const ushort* __restrict__ biasb, ushort* __restrict__ Oout) {
  int it = blockIdx.x, h = blockIdx.y, b = blockIdx.z;
  int i0 = it * 64;
  __shared__ char smem[65536];
  char* Ks = smem;           // [256 j][64 k] bf16 swizzled; later P[4][16][256]
  char* Vs = smem + 32768;   // [64 d][256 j] bf16 swizzled (V^T)
  const int tid = threadIdx.x, w = tid >> 6, ln = tid & 63;
  const int frow = ln & 15, fgrp = ln >> 4;
  // stage K
  {
    const int srow = ln >> 3, schunk = ln & 7;
#pragma unroll
    for (int q = 0; q < 8; ++q) {
      int inst = w * 8 + q;
      int row = inst * 8 + srow;  // j
      const char* g = (const char*)(qkv + (size_t)(row * 8 + b) * 2304 + 768 + h * 64) +
                      ((schunk * 16) ^ ((row & 7) << 4));
      gload_lds16(g, Ks + inst * 1024);
    }
    // stage V^T (rows d, 512B)
#pragma unroll
    for (int q = 0; q < 8; ++q) {
      int inst = w * 8 + q;
      int row = inst * 2 + (ln >> 5);
      int cb = (ln & 31) * 16;
      const char* g = (const char*)(vT + (size_t)((b * Hn + h) * 64 + row) * 256) +
                      (cb ^ ((row & 7) << 4));
      gload_lds16(g, Vs + inst * 1024);
    }
  }
  // Q fragments from global
  bf16x8 qf[2];
  {
    int qrow = i0 + w * 16 + frow;
    const ushort* qg = qkv + (size_t)(qrow * 8 + b) * 2304 + h * 64 + fgrp * 8;
    qf[0] = *(const bf16x8*)qg;
    qf[1] = *(const bf16x8*)(qg + 32);
  }
  __syncthreads();
  // QK^T
  f32x4 s[16];
#pragma unroll
  for (int jtl = 0; jtl < 16; ++jtl) {
    int row = jtl * 16 + frow;
    const char* kb = Ks + row * 128;
    bf16x8 k0 = *(const bf16x8*)(kb + ((fgrp * 16) ^ ((row & 7) << 4)));
    bf16x8 k1 = *(const bf16x8*)(kb + ((64 + fgrp * 16) ^ ((row & 7) << 4)));
    f32x4 t = {};
    t = MFMA16(qf[0], k0, t);
    t = MFMA16(qf[1], k1, t);
    s[jtl] = t;
  }
  // bias + scale + softmax (rows fgrp*4+r, cols frow+16*jtl)
  float inv[4];
#pragma unroll
  for (int r = 0; r < 4; ++r) {
    int i = i0 + w * 16 + fgrp * 4 + r;
    const ushort* brow = biasb + (((size_t)b * Hn + h) * Nn + i) * Nn;
    float m = -3.0e38f;
#pragma unroll
    for (int jtl = 0; jtl < 16; ++jtl) {
      float v = s[jtl][r] * SCALE + bf2f(brow[jtl * 16 + frow]);
      s[jtl][r] = v;
      m = fmaxf(m, v);
    }
    m = fmaxf(m, __shfl_xor(m, 1)); m = fmaxf(m, __shfl_xor(m, 2));
    m = fmaxf(m, __shfl_xor(m, 4)); m = fmaxf(m, __shfl_xor(m, 8));
    float su = 0.f;
#pragma unroll
    for (int jtl = 0; jtl < 16; ++jtl) {
      float p = __expf(s[jtl][r] - m);
      s[jtl][r] = p;
      su += p;
    }
    su += __shfl_xor(su, 1); su += __shfl_xor(su, 2);
    su += __shfl_xor(su, 4); su += __shfl_xor(su, 8);
    inv[r] = 1.0f / su;
  }
  __syncthreads();  // all waves done reading Ks
  // write P (unnormalized) into Ks region, per-wave [16][256] bf16 swizzled
  char* Ps = Ks + w * 8192;
#pragma unroll
  for (int r = 0; r < 4; ++r) {
    int prow = fgrp * 4 + r;
#pragma unroll
    for (int jtl = 0; jtl < 16; ++jtl) {
      int cb = jtl * 32 + frow * 2;
      *(ushort*)(Ps + prow * 512 + (cb ^ ((prow & 7) << 4))) = f2bf_t(s[jtl][r]);
    }
  }
  __syncthreads();
  // PV
  bf16x8 pf[8];
#pragma unroll
  for (int ks = 0; ks < 8; ++ks)
    pf[ks] = *(const bf16x8*)(Ps + frow * 512 + ((ks * 64 + fgrp * 16) ^ ((frow & 7) << 4)));
  f32x4 o[4] = {};
#pragma unroll
  for (int dt = 0; dt < 4; ++dt) {
#pragma unroll
    for (int ks = 0; ks < 8; ++ks) {
      int row = dt * 16 + frow;
      bf16x8 vf = *(const bf16x8*)(Vs + row * 512 + ((ks * 64 + fgrp * 16) ^ ((row & 7) << 4)));
      o[dt] = MFMA16(pf[ks], vf, o[dt]);
    }
  }
#pragma unroll
  for (int dt = 0; dt < 4; ++dt)
#pragma unroll
    for (int r = 0; r < 4; ++r) {
      int i = i0 + w * 16 + fgrp * 4 + r;
      Oout[(size_t)(i * 8 + b) * Dn + h * 64 + dt * 16 + frow] = f2bf(o[dt][r] * inv[r]);
    }
}

// ---------------- LayerNorm over D=768 ---------------------------------------
// MODE 0: bf16 out [T][D]; MODE 1: f32 out transposed to [B,N,D]
template <int MODE>
__global__ __launch_bounds__(256) void ln_kernel(
    const float* __restrict__ x, const float* __restrict__ sc,
    const float* __restrict__ bi, void* __restrict__ out) {
  int t = blockIdx.x;
  int tid = threadIdx.x;
  const float* xr = x + (size_t)t * Dn;
  float v0 = xr[tid], v1 = xr[tid + 256], v2 = xr[tid + 512];
  __shared__ float red[4], red2[4];
  float s = wave_sum(v0 + v1 + v2);
  if ((tid & 63) == 0) red[tid >> 6] = s;
  __syncthreads();
  float mean = (red[0] + red[1] + red[2] + red[3]) * (1.0f / 768.0f);
  float d0 = v0 - mean, d1 = v1 - mean, d2 = v2 - mean;
  float vs = wave_sum(d0 * d0 + d1 * d1 + d2 * d2);
  if ((tid & 63) == 0) red2[tid >> 6] = vs;
  __syncthreads();
  float var = (red2[0] + red2[1] + red2[2] + red2[3]) * (1.0f / 768.0f);
  float r = rsqrtf(var + 1e-5f);
  if (MODE == 0) {
    ushort* o = (ushort*)out + (size_t)t * Dn;
    o[tid]       = f2bf(d0 * r * sc[tid]       + bi[tid]);
    o[tid + 256] = f2bf(d1 * r * sc[tid + 256] + bi[tid + 256]);
    o[tid + 512] = f2bf(d2 * r * sc[tid + 512] + bi[tid + 512]);
  } else {
    int n = t >> 3, bb = t & 7;
    float* o = (float*)out + (size_t)(bb * Nn + n) * Dn;
    o[tid]       = d0 * r * sc[tid]       + bi[tid];
    o[tid + 256] = d1 * r * sc[tid + 256] + bi[tid + 256];
    o[tid + 512] = d2 * r * sc[tid + 512] + bi[tid + 512];
  }
}

// =============================================================================
extern "C" void kernel_launch(void* const* d_in, const int* in_sizes, int n_in,
                              void* d_out, int out_size, void* d_ws, size_t ws_size,
                              hipStream_t stream) {
  (void)in_sizes; (void)n_in; (void)out_size; (void)ws_size;
  const int*   atoms    = (const int*)  d_in[0];
  const float* pos      = (const float*)d_in[1];
  const float* atom_emb = (const float*)d_in[2];
  const float* gbf_means= (const float*)d_in[3];
  const float* gbf_stds = (const float*)d_in[4];
  const float* gbf_mul  = (const float*)d_in[5];
  const float* gbf_bias = (const float*)d_in[6];
  const float* bp_w1    = (const float*)d_in[7];
  const float* bp_b1    = (const float*)d_in[8];
  const float* bp_w2    = (const float*)d_in[9];
  const float* bp_b2    = (const float*)d_in[10];
  const float* edge_w   = (const float*)d_in[11];
  const float* edge_b   = (const float*)d_in[12];
  const float* ap_w     = (const float*)d_in[13];
  const float* ap_b     = (const float*)d_in[14];
  const float* ln1_s    = (const float*)d_in[15];
  const float* ln1_b    = (const float*)d_in[16];
  const float* wi       = (const float*)d_in[17];
  const float* bi       = (const float*)d_in[18];
  const float* wo       = (const float*)d_in[19];
  const float* bo       = (const float*)d_in[20];
  const float* ln2_s    = (const float*)d_in[21];
  const float* ln2_b    = (const float*)d_in[22];
  const float* w1       = (const float*)d_in[23];
  const float* b1       = (const float*)d_in[24];
  const float* w2       = (const float*)d_in[25];
  const float* b2       = (const float*)d_in[26];
  const float* fln_s    = (const float*)d_in[27];
  const float* fln_b    = (const float*)d_in[28];
  float* out = (float*)d_out;

  // workspace layout (u16 units unless noted)
  ushort* wsb   = (ushort*)d_ws;
  ushort* biasb = wsb;                                  // 6291456
  ushort* qkvb  = biasb + (size_t)Bn * Hn * Nn * Nn;    // 4718592 (also ffn mid, also apT)
  ushort* hb    = qkvb + (size_t)Tn * 2304;             // 1572864
  ushort* vT    = hb + (size_t)Tn * Dn;                 // 1572864 (efb overlays start)
  ushort* wiT   = vT + (size_t)Bn * Hn * 64 * 256;      // 7077888
  ushort* woT   = wiT + (size_t)4 * 2304 * Dn;          // 2359296
  ushort* w1T   = woT + (size_t)4 * Dn * Dn;            // 2359296
  ushort* w2T   = w1T + (size_t)4 * Dn * Dn;            // 2359296
  ushort* w1bT  = w2T + (size_t)4 * Dn * Dn;            // 16384
  float*  xbuf  = (float*)(w1bT + 16384);               // Tn*Dn f32
  ushort* apT   = qkvb;                                 // overlay (dead before qkv GEMM)
  ushort* ffnb  = qkvb;                                 // overlay (qkv dead in FFN phase)
  float*  efb   = (float*)vT;                           // overlay (dead before layer 0)

  // weight prep
  wtrans<<<dim3(12, 12, 1), 256, 0, stream>>>(ap_w, apT, 768, 768);
  wtrans<<<dim3(36, 12, 4), 256, 0, stream>>>(wi, wiT, 768, 2304);
  wtrans<<<dim3(12, 12, 4), 256, 0, stream>>>(wo, woT, 768, 768);
  wtrans<<<dim3(12, 12, 4), 256, 0, stream>>>(w1, w1T, 768, 768);
  wtrans<<<dim3(12, 12, 4), 256, 0, stream>>>(w2, w2T, 768, 768);
  wtrans<<<dim3(2, 2, 1), 256, 0, stream>>>(bp_w1, w1bT, 128, 128);

  dim3 gridNB(Nn, Bn);
  ef_kernel<<<gridNB, 128, 0, stream>>>(atoms, pos, gbf_means, gbf_stds, gbf_mul, gbf_bias, efb);
  gbias_kernel<<<gridNB, 256, 0, stream>>>(atoms, pos, gbf_means, gbf_stds,
                                           gbf_mul, gbf_bias, w1bT, bp_b1, bp_w2, bp_b2, biasb);
  node_kernel<<<gridNB, 256, 0, stream>>>(atoms, efb, atom_emb, edge_w, edge_b, hb);
  mgemm<3><<<dim3(12, 32), 256, 0, stream>>>(hb, apT, ap_b, nullptr, xbuf, Tn, Dn, Dn);

  for (int it = 0; it < 8; ++it) {
    int l = it & 3;
    ln_kernel<0><<<Tn, 256, 0, stream>>>(xbuf, ln1_s + l * Dn, ln1_b + l * Dn, hb);
    mgemm128<0><<<dim3(18, 16), 256, 0, stream>>>(hb, wiT + (size_t)l * 2304 * Dn,
                                                  bi + l * 2304, nullptr, qkvb, Tn, Dn, 2304);
    vtrans<<<dim3(Hn, Bn), 256, 0, stream>>>(qkvb, vT);
    attn_mfma<<<dim3(4, Hn, Bn), 256, 0, stream>>>(qkvb, vT, biasb, hb);
    mgemm<2><<<dim3(12, 32), 256, 0, stream>>>(hb, woT + (size_t)l * Dn * Dn,
                                               bo + l * Dn, xbuf, xbuf, Tn, Dn, Dn);
    ln_kernel<0><<<Tn, 256, 0, stream>>>(xbuf, ln2_s + l * Dn, ln2_b + l * Dn, hb);
    mgemm<1><<<dim3(12, 32), 256, 0, stream>>>(hb, w1T + (size_t)l * Dn * Dn,
                                               b1 + l * Dn, nullptr, ffnb, Tn, Dn, Dn);
    mgemm<2><<<dim3(12, 32), 256, 0, stream>>>(ffnb, w2T + (size_t)l * Dn * Dn,
                                               b2 + l * Dn, xbuf, xbuf, Tn, Dn, Dn);
  }
  ln_kernel<1><<<Tn, 256, 0, stream>>>(xbuf, fln_s, fln_b, out);
}

// Round 7
// 781.060 us; speedup vs baseline: 1.4650x; 1.1238x over previous
//
#include <hip/hip_runtime.h>
#include <math.h>

constexpr int Bn = 8, Nn = 256, Dn = 768, Hn = 12, Kn = 128;
constexpr int Tn = Nn * Bn;      // 2048 tokens, [B,N] order
constexpr float SCALE = 0.125f;  // HD^-0.5, HD=64
constexpr float NEGB = -1e9f;

typedef __attribute__((ext_vector_type(8))) short bf16x8;
typedef __attribute__((ext_vector_type(4))) float f32x4;

#define MFMA16(a, b, c) __builtin_amdgcn_mfma_f32_16x16x32_bf16((a), (b), (c), 0, 0, 0)

__device__ __forceinline__ void gload_lds16(const void* g, void* l) {
  __builtin_amdgcn_global_load_lds(
      (const __attribute__((address_space(1))) void*)g,
      (__attribute__((address_space(3))) void*)l, 16, 0, 0);
}

__device__ __forceinline__ ushort f2bf(float x) {  // round-to-nearest-even
  union { float f; unsigned u; } v; v.f = x;
  unsigned r = (v.u + 0x7fff + ((v.u >> 16) & 1)) >> 16;
  return (ushort)r;
}
__device__ __forceinline__ ushort f2bf_t(float x) {  // truncate (1 inst)
  union { float f; unsigned u; } v; v.f = x;
  return (ushort)(v.u >> 16);
}
__device__ __forceinline__ float bf2f(ushort u) {
  union { unsigned u; float f; } v; v.u = ((unsigned)u) << 16;
  return v.f;
}
// tanh-approx gelu (|err| <~3e-3)
__device__ __forceinline__ float gelu_fast(float x) {
  float u = x * (0.7978845608f + 0.0356774081f * x * x);
  float e = __expf(2.0f * u);
  float t = 1.0f - 2.0f / (e + 1.0f);
  return 0.5f * x * (1.0f + t);
}
__device__ __forceinline__ float wave_sum(float v) {
#pragma unroll
  for (int off = 32; off; off >>= 1) v += __shfl_xor(v, off);
  return v;
}

// ---------------- weight transpose+convert: W[K,N] f32 -> WT[N,K] bf16 -------
__global__ __launch_bounds__(256) void wtrans(const float* __restrict__ W,
                                              ushort* __restrict__ WT,
                                              int Kd, int Nd) {
  __shared__ float tile[64][65];
  const float* Wl = W + (size_t)blockIdx.z * Kd * Nd;
  ushort* WTl = WT + (size_t)blockIdx.z * Kd * Nd;
  int n0 = blockIdx.x * 64, k0 = blockIdx.y * 64;
  int tid = threadIdx.x;
  for (int e = tid; e < 64 * 64; e += 256) {
    int r = e >> 6, c = e & 63;
    tile[r][c] = Wl[(size_t)(k0 + r) * Nd + n0 + c];
  }
  __syncthreads();
  for (int e = tid; e < 64 * 64; e += 256) {
    int r = e >> 6, c = e & 63;
    WTl[(size_t)(n0 + r) * Kd + k0 + c] = f2bf(tile[c][r]);
  }
}

// ---------------- Gaussian edge features: ef[b,i,k] = sum_j (!pad_j) gauss ----
__global__ __launch_bounds__(128) void ef_kernel(
    const int* __restrict__ atoms, const float* __restrict__ pos,
    const float* __restrict__ means, const float* __restrict__ stds,
    const float* __restrict__ gmul, const float* __restrict__ gbias,
    float* __restrict__ ef) {
  int i = blockIdx.x, b = blockIdx.y;
  __shared__ float dist[Nn], ml[Nn], bs2[Nn];
  __shared__ int padm[Nn];
  int tid = threadIdx.x;
  int ai = atoms[b * Nn + i];
  float px = pos[(b * Nn + i) * 3], py = pos[(b * Nn + i) * 3 + 1], pz = pos[(b * Nn + i) * 3 + 2];
  for (int j = tid; j < Nn; j += 128) {
    int aj = atoms[b * Nn + j];
    float dx = px - pos[(b * Nn + j) * 3];
    float dy = py - pos[(b * Nn + j) * 3 + 1];
    float dz = pz - pos[(b * Nn + j) * 3 + 2];
    float sq = dx * dx + dy * dy + dz * dz;
    dist[j] = sq > 0.f ? sqrtf(sq) : 0.f;
    int et = ai * 10 + aj;
    ml[j] = gmul[et];
    bs2[j] = gbias[et];
    padm[j] = (aj == 0);
  }
  __syncthreads();
  int k = tid;
  float mean = means[k];
  float sd = fabsf(stds[k]) + 1e-5f;
  float inv = 1.0f / sd;
  float cn = 1.0f / (sqrtf(2.0f * 3.14159f) * sd);
  float acc = 0.f;
  for (int j = 0; j < Nn; ++j) {
    if (padm[j]) continue;
    float t = (ml[j] * dist[j] + bs2[j] - mean) * inv;
    acc += __expf(-0.5f * t * t);
  }
  ef[(b * Nn + i) * Kn + k] = acc * cn;
}

// ---------------- bias MLP, all-MFMA, W1 staged to LDS (R4 structure) --------
__global__ __launch_bounds__(256) void gbias_kernel(
    const int* __restrict__ atoms, const float* __restrict__ pos,
    const float* __restrict__ means, const float* __restrict__ stds,
    const float* __restrict__ gmul, const float* __restrict__ gbias_,
    const ushort* __restrict__ w1T, const float* __restrict__ b1,
    const float* __restrict__ w2, const float* __restrict__ b2,
    ushort* __restrict__ biasb) {
  int i = blockIdx.x, b = blockIdx.y;
  __shared__ char W1s[32768];      // [128 n][128 k] bf16, XOR-swizzled; persists
  __shared__ char Ag[16384];       // phase B: gbf [64 j][128 k] / then g [64 j][128 n]
  __shared__ char W2s[4096];       // [16 h][128 n] bf16, XOR-swizzled (B-operand)
  __shared__ float sj[256];        // ml*dist+bs per j
  __shared__ int pml[256];
  __shared__ float b1s[128], invs_[128], mui[128], cns[128];
  const int tid = threadIdx.x, w = tid >> 6, ln = tid & 63;
  const int frow = ln & 15, fgrp = ln >> 4;
  // stage W1T once (pre-swizzled source -> linear LDS; read side applies swizzle)
  {
    int srow = ln >> 4, sc = ln & 15;
#pragma unroll
    for (int q = 0; q < 8; ++q) {
      int inst = w * 8 + q;
      int row = inst * 4 + srow;
      const char* g = (const char*)(w1T + row * 128) + ((sc * 16) ^ ((row & 7) << 4));
      gload_lds16(g, W1s + inst * 1024);
    }
  }
  if (tid < 128) {
    float mean = means[tid];
    float sd = fabsf(stds[tid]) + 1e-5f;
    float inv = 1.0f / sd;
    invs_[tid] = inv;
    mui[tid] = mean * inv;
    cns[tid] = inv * 0.3989423f;  // 1/sqrt(2*3.14159)
    b1s[tid] = b1[tid];
  }
  // W2 as B-operand: [16 h][128 n] bf16 rows, swizzled; h>=12 rows zero
  for (int e = tid; e < 2048; e += 256) {
    int h = e >> 7, k = e & 127;
    float v = (h < 12) ? w2[k * 12 + h] : 0.f;
    *(ushort*)(W2s + h * 256 + ((2 * k) ^ ((h & 7) << 4))) = f2bf(v);
  }
  {
    int ai = atoms[b * Nn + i];
    int j = tid;
    int aj = atoms[b * Nn + j];
    float dx = pos[(b * Nn + i) * 3]     - pos[(b * Nn + j) * 3];
    float dy = pos[(b * Nn + i) * 3 + 1] - pos[(b * Nn + j) * 3 + 1];
    float dz = pos[(b * Nn + i) * 3 + 2] - pos[(b * Nn + j) * 3 + 2];
    float sq = dx * dx + dy * dy + dz * dz;
    float d = sq > 0.f ? sqrtf(sq) : 0.f;
    int et = ai * 10 + aj;
    sj[j] = fmaf(gmul[et], d, gbias_[et]);
    pml[j] = (aj == 0);
  }
  __syncthreads();

  for (int jt = 0; jt < 4; ++jt) {
    int j0 = jt * 64;
    // build Ag: gbf tile [64 j][128 k] bf16 swizzled; thread k = tid&127
    {
      int k = tid & 127;
      float inv = invs_[k], mu = mui[k], cn = cns[k];
      int r0 = (tid >> 7) * 32;
#pragma unroll 8
      for (int rr = 0; rr < 32; ++rr) {
        int row = r0 + rr;
        float t = fmaf(inv, sj[j0 + row], -mu);
        float g = __expf(-0.5f * t * t) * cn;
        *(ushort*)(Ag + row * 256 + ((2 * k) ^ ((row & 7) << 4))) = f2bf_t(g);
      }
    }
    __syncthreads();
    // phase B: [64,128]@[128,128] via MFMA; wave w owns j-rows w*16..+16
    f32x4 acc[8] = {};
    const int arow = w * 16 + frow;
#pragma unroll
    for (int ks = 0; ks < 4; ++ks) {
      bf16x8 af = *(const bf16x8*)(Ag + arow * 256 + ((ks * 64 + fgrp * 16) ^ ((arow & 7) << 4)));
#pragma unroll
      for (int nt = 0; nt < 8; ++nt) {
        int brow = nt * 16 + frow;
        bf16x8 bfv = *(const bf16x8*)(W1s + brow * 256 + ((ks * 64 + fgrp * 16) ^ ((brow & 7) << 4)));
        acc[nt] = MFMA16(af, bfv, acc[nt]);
      }
    }
    __syncthreads();  // Ag (gbf) reads done; reuse as g[j][n]
    // gelu + store g[j][n] bf16 swizzled (A-operand-ready)
#pragma unroll
    for (int nt = 0; nt < 8; ++nt) {
      int n = nt * 16 + frow;
#pragma unroll
      for (int r = 0; r < 4; ++r) {
        int jloc = w * 16 + fgrp * 4 + r;
        float g = gelu_fast(acc[nt][r] + b1s[n]);
        *(ushort*)(Ag + jloc * 256 + ((2 * n) ^ ((jloc & 7) << 4))) = f2bf_t(g);
      }
    }
    __syncthreads();
    // phase C: [64,128]@[128,16] via MFMA -> out[j][h]
    {
      f32x4 acc2 = {};
      int jrow = w * 16 + frow;
#pragma unroll
      for (int ks = 0; ks < 4; ++ks) {
        bf16x8 af = *(const bf16x8*)(Ag + jrow * 256 + ((ks * 64 + fgrp * 16) ^ ((jrow & 7) << 4)));
        bf16x8 bfv = *(const bf16x8*)(W2s + frow * 256 + ((ks * 64 + fgrp * 16) ^ ((frow & 7) << 4)));
        acc2 = MFMA16(af, bfv, acc2);
      }
      if (frow < 12) {
        float bv = b2[frow];
#pragma unroll
        for (int r = 0; r < 4; ++r) {
          int jl = w * 16 + fgrp * 4 + r;
          int jg = j0 + jl;
          float v = pml[jg] ? NEGB : (acc2[r] + bv);
          biasb[(((size_t)b * Hn + frow) * Nn + i) * Nn + jg] = f2bf(v);
        }
      }
    }
    __syncthreads();  // before next jt overwrites Ag
  }
}

// ---------------- node = emb[atoms] + ef@edge_w + edge_b -> [B,N,D] bf16 ------
__global__ __launch_bounds__(256) void node_kernel(
    const int* __restrict__ atoms, const float* __restrict__ ef,
    const float* __restrict__ emb, const float* __restrict__ ew,
    const float* __restrict__ eb, ushort* __restrict__ nodeT) {
  int n = blockIdx.x, b = blockIdx.y;
  __shared__ float efs[Kn];
  int tid = threadIdx.x;
  if (tid < Kn) efs[tid] = ef[(b * Nn + n) * Kn + tid];
  __syncthreads();
  int a = atoms[b * Nn + n];
  for (int d = tid; d < Dn; d += 256) {
    float acc = emb[a * Dn + d] + eb[d];
#pragma unroll 8
    for (int k = 0; k < Kn; ++k) acc += efs[k] * ew[k * Dn + d];
    nodeT[(size_t)(b * Nn + n) * Dn + d] = f2bf(acc);
  }
}

// ---------------- MFMA GEMM 64x64 tile (for N=768 GEMMs; 384-block grid) -----
// MODE 0: bf16 out; 1: gelu bf16 out; 2: f32 out + residual; 3: f32 out
template <int MODE>
__global__ __launch_bounds__(256, 4) void mgemm(
    const ushort* __restrict__ A, const ushort* __restrict__ WT,
    const float* __restrict__ bias, const float* __restrict__ res,
    void* __restrict__ Cout, int M, int Kd, int Nd) {
  __shared__ char smem[16384];
  char* ldsA = smem;
  char* ldsB = smem + 8192;
  const int tid = threadIdx.x, w = tid >> 6, ln = tid & 63;
  const int m0 = blockIdx.y * 64, n0 = blockIdx.x * 64;
  const int wm = (w >> 1) * 32, wn = (w & 1) * 32;
  const int srow = ln >> 3, schunk = ln & 7;
  const int sswz = (schunk * 16) ^ (srow << 4);
  const int frow = ln & 15, fgrp = ln >> 4;
  f32x4 acc[2][2] = {};
  for (int kt = 0; kt < Kd; kt += 64) {
    __syncthreads();
#pragma unroll
    for (int q = 0; q < 2; ++q) {
      int r = (w * 2 + q) * 8 + srow;
      gload_lds16((const char*)(A + (size_t)(m0 + r) * Kd + kt) + sswz, ldsA + (w * 2 + q) * 1024);
    }
#pragma unroll
    for (int q = 0; q < 2; ++q) {
      int r = (w * 2 + q) * 8 + srow;
      gload_lds16((const char*)(WT + (size_t)(n0 + r) * Kd + kt) + sswz, ldsB + (w * 2 + q) * 1024);
    }
    __syncthreads();
#pragma unroll
    for (int ks = 0; ks < 2; ++ks) {
      bf16x8 af[2], bfv[2];
#pragma unroll
      for (int mt = 0; mt < 2; ++mt) {
        int row = wm + mt * 16 + frow;
        af[mt] = *(const bf16x8*)(ldsA + row * 128 + ((ks * 64 + fgrp * 16) ^ ((row & 7) << 4)));
      }
#pragma unroll
      for (int nt = 0; nt < 2; ++nt) {
        int row = wn + nt * 16 + frow;
        bfv[nt] = *(const bf16x8*)(ldsB + row * 128 + ((ks * 64 + fgrp * 16) ^ ((row & 7) << 4)));
      }
      acc[0][0] = MFMA16(af[0], bfv[0], acc[0][0]);
      acc[0][1] = MFMA16(af[0], bfv[1], acc[0][1]);
      acc[1][0] = MFMA16(af[1], bfv[0], acc[1][0]);
      acc[1][1] = MFMA16(af[1], bfv[1], acc[1][1]);
    }
  }
#pragma unroll
  for (int nt = 0; nt < 2; ++nt) {
    int n = n0 + wn + nt * 16 + frow;
    float bv = bias[n];
#pragma unroll
    for (int mt = 0; mt < 2; ++mt) {
#pragma unroll
      for (int r = 0; r < 4; ++r) {
        int m = m0 + wm + mt * 16 + fgrp * 4 + r;
        float v = acc[mt][nt][r] + bv;
        if (MODE == 1) v = gelu_fast(v);
        if (MODE == 2) v += res[(size_t)m * Nd + n];
        if (MODE <= 1) ((ushort*)Cout)[(size_t)m * Nd + n] = f2bf(v);
        else           ((float*)Cout)[(size_t)m * Nd + n] = v;
      }
    }
  }
}

// ---------------- MFMA GEMM 128x128 tile -------------------------------------
// MODE 0: bf16 out; MODE 4: qkv out — n<1536 row-major bf16, n>=1536 into vT[b,h,d,j]
template <int MODE>
__global__ __launch_bounds__(256, 2) void mgemm128(
    const ushort* __restrict__ A, const ushort* __restrict__ WT,
    const float* __restrict__ bias, ushort* __restrict__ vTout,
    void* __restrict__ Cout, int M, int Kd, int Nd) {
  __shared__ char smem[32768];
  char* ldsA = smem;
  char* ldsB = smem + 16384;
  const int tid = threadIdx.x, w = tid >> 6, ln = tid & 63;
  const int m0 = blockIdx.y * 128, n0 = blockIdx.x * 128;
  const int wm = (w >> 1) * 64, wn = (w & 1) * 64;
  const int srow = ln >> 3, schunk = ln & 7;
  const int sswz = (schunk * 16) ^ (srow << 4);
  const int frow = ln & 15, fgrp = ln >> 4;
  f32x4 acc[4][4] = {};
  for (int kt = 0; kt < Kd; kt += 64) {
    __syncthreads();
#pragma unroll
    for (int q = 0; q < 4; ++q) {
      int r = (w * 4 + q) * 8 + srow;
      gload_lds16((const char*)(A + (size_t)(m0 + r) * Kd + kt) + sswz, ldsA + (w * 4 + q) * 1024);
    }
#pragma unroll
    for (int q = 0; q < 4; ++q) {
      int r = (w * 4 + q) * 8 + srow;
      gload_lds16((const char*)(WT + (size_t)(n0 + r) * Kd + kt) + sswz, ldsB + (w * 4 + q) * 1024);
    }
    __syncthreads();
#pragma unroll
    for (int ks = 0; ks < 2; ++ks) {
      bf16x8 af[4], bfv[4];
#pragma unroll
      for (int mt = 0; mt < 4; ++mt) {
        int row = wm + mt * 16 + frow;
        af[mt] = *(const bf16x8*)(ldsA + row * 128 + ((ks * 64 + fgrp * 16) ^ ((row & 7) << 4)));
      }
#pragma unroll
      for (int nt = 0; nt < 4; ++nt) {
        int row = wn + nt * 16 + frow;
        bfv[nt] = *(const bf16x8*)(ldsB + row * 128 + ((ks * 64 + fgrp * 16) ^ ((row & 7) << 4)));
      }
#pragma unroll
      for (int mt = 0; mt < 4; ++mt)
#pragma unroll
        for (int nt = 0; nt < 4; ++nt)
          acc[mt][nt] = MFMA16(af[mt], bfv[nt], acc[mt][nt]);
    }
  }
#pragma unroll
  for (int nt = 0; nt < 4; ++nt) {
    int n = n0 + wn + nt * 16 + frow;
    float bv = bias[n];
    if (MODE == 4 && n >= 1536) {
      // V: write transposed into vT[b][h][d][j]; (b,h,d) uniform per 16-lane grp
      int dd = n - 1536, h = dd >> 6, d = dd & 63;
#pragma unroll
      for (int mt = 0; mt < 4; ++mt) {
#pragma unroll
        for (int r = 0; r < 4; ++r) {
          int m = m0 + wm + mt * 16 + fgrp * 4 + r;
          int bb = m >> 8, j = m & 255;
          vTout[(((size_t)bb * Hn + h) * 64 + d) * 256 + j] = f2bf(acc[mt][nt][r] + bv);
        }
      }
    } else {
#pragma unroll
      for (int mt = 0; mt < 4; ++mt) {
#pragma unroll
        for (int r = 0; r < 4; ++r) {
          int m = m0 + wm + mt * 16 + fgrp * 4 + r;
          ((ushort*)Cout)[(size_t)m * Nd + n] = f2bf(acc[mt][nt][r] + bv);
        }
      }
    }
  }
}

// ---------------- MFMA attention: block = (b, h, 64 i-rows); tokens [B,N] ----
__global__ __launch_bounds__(256, 2) void attn_mfma(
    const ushort* __restrict__ qkv, const ushort* __restrict__ vT,
    const ushort* __restrict__ biasb, ushort* __restrict__ Oout) {
  int it = blockIdx.x, h = blockIdx.y, b = blockIdx.z;
  int i0 = it * 64;
  __shared__ char smem[65536];
  char* Ks = smem;           // [256 j][64 k] bf16 swizzled; later P[4][16][256]
  char* Vs = smem + 32768;   // [64 d][256 j] bf16 swizzled (V^T)
  const int tid = threadIdx.x, w = tid >> 6, ln = tid & 63;
  const int frow = ln & 15, fgrp = ln >> 4;
  // stage K
  {
    const int srow = ln >> 3, schunk = ln & 7;
#pragma unroll
    for (int q = 0; q < 8; ++q) {
      int inst = w * 8 + q;
      int row = inst * 8 + srow;  // j
      const char* g = (const char*)(qkv + (size_t)(b * Nn + row) * 2304 + 768 + h * 64) +
                      ((schunk * 16) ^ ((row & 7) << 4));
      gload_lds16(g, Ks + inst * 1024);
    }
    // stage V^T (rows d, 512B)
#pragma unroll
    for (int q = 0; q < 8; ++q) {
      int inst = w * 8 + q;
      int row = inst * 2 + (ln >> 5);
      int cb = (ln & 31) * 16;
      const char* g = (const char*)(vT + (size_t)((b * Hn + h) * 64 + row) * 256) +
                      (cb ^ ((row & 7) << 4));
      gload_lds16(g, Vs + inst * 1024);
    }
  }
  // Q fragments from global
  bf16x8 qf[2];
  {
    int qrow = i0 + w * 16 + frow;
    const ushort* qg = qkv + (size_t)(b * Nn + qrow) * 2304 + h * 64 + fgrp * 8;
    qf[0] = *(const bf16x8*)qg;
    qf[1] = *(const bf16x8*)(qg + 32);
  }
  __syncthreads();
  // QK^T
  f32x4 s[16];
#pragma unroll
  for (int jtl = 0; jtl < 16; ++jtl) {
    int row = jtl * 16 + frow;
    const char* kb = Ks + row * 128;
    bf16x8 k0 = *(const bf16x8*)(kb + ((fgrp * 16) ^ ((row & 7) << 4)));
    bf16x8 k1 = *(const bf16x8*)(kb + ((64 + fgrp * 16) ^ ((row & 7) << 4)));
    f32x4 t = {};
    t = MFMA16(qf[0], k0, t);
    t = MFMA16(qf[1], k1, t);
    s[jtl] = t;
  }
  // bias + scale + softmax (rows fgrp*4+r, cols frow+16*jtl)
  float inv[4];
#pragma unroll
  for (int r = 0; r < 4; ++r) {
    int i = i0 + w * 16 + fgrp * 4 + r;
    const ushort* brow = biasb + (((size_t)b * Hn + h) * Nn + i) * Nn;
    float m = -3.0e38f;
#pragma unroll
    for (int jtl = 0; jtl < 16; ++jtl) {
      float v = s[jtl][r] * SCALE + bf2f(brow[jtl * 16 + frow]);
      s[jtl][r] = v;
      m = fmaxf(m, v);
    }
    m = fmaxf(m, __shfl_xor(m, 1)); m = fmaxf(m, __shfl_xor(m, 2));
    m = fmaxf(m, __shfl_xor(m, 4)); m = fmaxf(m, __shfl_xor(m, 8));
    float su = 0.f;
#pragma unroll
    for (int jtl = 0; jtl < 16; ++jtl) {
      float p = __expf(s[jtl][r] - m);
      s[jtl][r] = p;
      su += p;
    }
    su += __shfl_xor(su, 1); su += __shfl_xor(su, 2);
    su += __shfl_xor(su, 4); su += __shfl_xor(su, 8);
    inv[r] = 1.0f / su;
  }
  __syncthreads();  // all waves done reading Ks
  // write P (unnormalized) into Ks region, per-wave [16][256] bf16 swizzled
  char* Ps = Ks + w * 8192;
#pragma unroll
  for (int r = 0; r < 4; ++r) {
    int prow = fgrp * 4 + r;
#pragma unroll
    for (int jtl = 0; jtl < 16; ++jtl) {
      int cb = jtl * 32 + frow * 2;
      *(ushort*)(Ps + prow * 512 + (cb ^ ((prow & 7) << 4))) = f2bf_t(s[jtl][r]);
    }
  }
  __syncthreads();
  // PV
  bf16x8 pf[8];
#pragma unroll
  for (int ks = 0; ks < 8; ++ks)
    pf[ks] = *(const bf16x8*)(Ps + frow * 512 + ((ks * 64 + fgrp * 16) ^ ((frow & 7) << 4)));
  f32x4 o[4] = {};
#pragma unroll
  for (int dt = 0; dt < 4; ++dt) {
#pragma unroll
    for (int ks = 0; ks < 8; ++ks) {
      int row = dt * 16 + frow;
      bf16x8 vf = *(const bf16x8*)(Vs + row * 512 + ((ks * 64 + fgrp * 16) ^ ((row & 7) << 4)));
      o[dt] = MFMA16(pf[ks], vf, o[dt]);
    }
  }
#pragma unroll
  for (int dt = 0; dt < 4; ++dt)
#pragma unroll
    for (int r = 0; r < 4; ++r) {
      int i = i0 + w * 16 + fgrp * 4 + r;
      Oout[(size_t)(b * Nn + i) * Dn + h * 64 + dt * 16 + frow] = f2bf(o[dt][r] * inv[r]);
    }
}

// ---------------- LayerNorm over D=768 ---------------------------------------
// MODE 0: bf16 out [T][D]; MODE 1: f32 out [T][D] (tokens already [B,N])
template <int MODE>
__global__ __launch_bounds__(256) void ln_kernel(
    const float* __restrict__ x, const float* __restrict__ sc,
    const float* __restrict__ bi, void* __restrict__ out) {
  int t = blockIdx.x;
  int tid = threadIdx.x;
  const float* xr = x + (size_t)t * Dn;
  float v0 = xr[tid], v1 = xr[tid + 256], v2 = xr[tid + 512];
  __shared__ float red[4], red2[4];
  float s = wave_sum(v0 + v1 + v2);
  if ((tid & 63) == 0) red[tid >> 6] = s;
  __syncthreads();
  float mean = (red[0] + red[1] + red[2] + red[3]) * (1.0f / 768.0f);
  float d0 = v0 - mean, d1 = v1 - mean, d2 = v2 - mean;
  float vs = wave_sum(d0 * d0 + d1 * d1 + d2 * d2);
  if ((tid & 63) == 0) red2[tid >> 6] = vs;
  __syncthreads();
  float var = (red2[0] + red2[1] + red2[2] + red2[3]) * (1.0f / 768.0f);
  float r = rsqrtf(var + 1e-5f);
  if (MODE == 0) {
    ushort* o = (ushort*)out + (size_t)t * Dn;
    o[tid]       = f2bf(d0 * r * sc[tid]       + bi[tid]);
    o[tid + 256] = f2bf(d1 * r * sc[tid + 256] + bi[tid + 256]);
    o[tid + 512] = f2bf(d2 * r * sc[tid + 512] + bi[tid + 512]);
  } else {
    float* o = (float*)out + (size_t)t * Dn;
    o[tid]       = d0 * r * sc[tid]       + bi[tid];
    o[tid + 256] = d1 * r * sc[tid + 256] + bi[tid + 256];
    o[tid + 512] = d2 * r * sc[tid + 512] + bi[tid + 512];
  }
}

// =============================================================================
extern "C" void kernel_launch(void* const* d_in, const int* in_sizes, int n_in,
                              void* d_out, int out_size, void* d_ws, size_t ws_size,
                              hipStream_t stream) {
  (void)in_sizes; (void)n_in; (void)out_size; (void)ws_size;
  const int*   atoms    = (const int*)  d_in[0];
  const float* pos      = (const float*)d_in[1];
  const float* atom_emb = (const float*)d_in[2];
  const float* gbf_means= (const float*)d_in[3];
  const float* gbf_stds = (const float*)d_in[4];
  const float* gbf_mul  = (const float*)d_in[5];
  const float* gbf_bias = (const float*)d_in[6];
  const float* bp_w1    = (const float*)d_in[7];
  const float* bp_b1    = (const float*)d_in[8];
  const float* bp_w2    = (const float*)d_in[9];
  const float* bp_b2    = (const float*)d_in[10];
  const float* edge_w   = (const float*)d_in[11];
  const float* edge_b   = (const float*)d_in[12];
  const float* ap_w     = (const float*)d_in[13];
  const float* ap_b     = (const float*)d_in[14];
  const float* ln1_s    = (const float*)d_in[15];
  const float* ln1_b    = (const float*)d_in[16];
  const float* wi       = (const float*)d_in[17];
  const float* bi       = (const float*)d_in[18];
  const float* wo       = (const float*)d_in[19];
  const float* bo       = (const float*)d_in[20];
  const float* ln2_s    = (const float*)d_in[21];
  const float* ln2_b    = (const float*)d_in[22];
  const float* w1       = (const float*)d_in[23];
  const float* b1       = (const float*)d_in[24];
  const float* w2       = (const float*)d_in[25];
  const float* b2       = (const float*)d_in[26];
  const float* fln_s    = (const float*)d_in[27];
  const float* fln_b    = (const float*)d_in[28];
  float* out = (float*)d_out;

  // workspace layout (u16 units unless noted)
  ushort* wsb   = (ushort*)d_ws;
  ushort* biasb = wsb;                                  // 6291456
  ushort* qkvb  = biasb + (size_t)Bn * Hn * Nn * Nn;    // 4718592 (also ffn mid, also apT)
  ushort* hb    = qkvb + (size_t)Tn * 2304;             // 1572864
  ushort* vT    = hb + (size_t)Tn * Dn;                 // 1572864 (efb overlays start)
  ushort* wiT   = vT + (size_t)Bn * Hn * 64 * 256;      // 7077888
  ushort* woT   = wiT + (size_t)4 * 2304 * Dn;          // 2359296
  ushort* w1T   = woT + (size_t)4 * Dn * Dn;            // 2359296
  ushort* w2T   = w1T + (size_t)4 * Dn * Dn;            // 2359296
  ushort* w1bT  = w2T + (size_t)4 * Dn * Dn;            // 16384
  float*  xbuf  = (float*)(w1bT + 16384);               // Tn*Dn f32
  ushort* apT   = qkvb;                                 // overlay (dead before qkv GEMM)
  ushort* ffnb  = qkvb;                                 // overlay (qkv dead in FFN phase)
  float*  efb   = (float*)vT;                           // overlay (dead before layer 0)

  // weight prep
  wtrans<<<dim3(12, 12, 1), 256, 0, stream>>>(ap_w, apT, 768, 768);
  wtrans<<<dim3(36, 12, 4), 256, 0, stream>>>(wi, wiT, 768, 2304);
  wtrans<<<dim3(12, 12, 4), 256, 0, stream>>>(wo, woT, 768, 768);
  wtrans<<<dim3(12, 12, 4), 256, 0, stream>>>(w1, w1T, 768, 768);
  wtrans<<<dim3(12, 12, 4), 256, 0, stream>>>(w2, w2T, 768, 768);
  wtrans<<<dim3(2, 2, 1), 256, 0, stream>>>(bp_w1, w1bT, 128, 128);

  dim3 gridNB(Nn, Bn);
  ef_kernel<<<gridNB, 128, 0, stream>>>(atoms, pos, gbf_means, gbf_stds, gbf_mul, gbf_bias, efb);
  gbias_kernel<<<gridNB, 256, 0, stream>>>(atoms, pos, gbf_means, gbf_stds,
                                           gbf_mul, gbf_bias, w1bT, bp_b1, bp_w2, bp_b2, biasb);
  node_kernel<<<gridNB, 256, 0, stream>>>(atoms, efb, atom_emb, edge_w, edge_b, hb);
  mgemm<3><<<dim3(12, 32), 256, 0, stream>>>(hb, apT, ap_b, nullptr, xbuf, Tn, Dn, Dn);

  for (int it = 0; it < 8; ++it) {
    int l = it & 3;
    ln_kernel<0><<<Tn, 256, 0, stream>>>(xbuf, ln1_s + l * Dn, ln1_b + l * Dn, hb);
    mgemm128<4><<<dim3(18, 16), 256, 0, stream>>>(hb, wiT + (size_t)l * 2304 * Dn,
                                                  bi + l * 2304, vT, qkvb, Tn, Dn, 2304);
    attn_mfma<<<dim3(4, Hn, Bn), 256, 0, stream>>>(qkvb, vT, biasb, hb);
    mgemm<2><<<dim3(12, 32), 256, 0, stream>>>(hb, woT + (size_t)l * Dn * Dn,
                                               bo + l * Dn, xbuf, xbuf, Tn, Dn, Dn);
    ln_kernel<0><<<Tn, 256, 0, stream>>>(xbuf, ln2_s + l * Dn, ln2_b + l * Dn, hb);
    mgemm<1><<<dim3(12, 32), 256, 0, stream>>>(hb, w1T + (size_t)l * Dn * Dn,
                                               b1 + l * Dn, nullptr, ffnb, Tn, Dn, Dn);
    mgemm<2><<<dim3(12, 32), 256, 0, stream>>>(ffnb, w2T + (size_t)l * Dn * Dn,
                                               b2 + l * Dn, xbuf, xbuf, Tn, Dn, Dn);
  }
  ln_kernel<1><<<Tn, 256, 0, stream>>>(xbuf, fln_s, fln_b, out);
}